// Round 6
// baseline (2243.591 us; speedup 1.0000x reference)
//
#include <hip/hip_runtime.h>

// ---------------------------------------------------------------------------
// RWKV6 Tmix (B=4,T=2048,C=2048,H=32,HS=64). Inputs fp32, OUTPUT FP32
// (round-5 bisect: identical err across two pipelines => shared output-dtype
// bug; harness doc says d_out dtype = reference output dtype = float32).
// MFMA pipeline (round 4) + MODE 5 fp32 final store.
// ---------------------------------------------------------------------------

#define Cdim 2048
#define Tdim 2048

using short8 = __attribute__((ext_vector_type(8))) short;   // 8 x bf16
using f32x4  = __attribute__((ext_vector_type(4))) float;
using us4    = __attribute__((ext_vector_type(4))) unsigned short;
typedef unsigned short ushort_t;

__device__ __forceinline__ float b2f(unsigned short h) {
    union { unsigned int u; float f; } x; x.u = ((unsigned int)h) << 16; return x.f;
}
__device__ __forceinline__ unsigned short f2b(float f) {
    union { float f; unsigned int u; } x; x.f = f;
    unsigned int r = x.u + 0x7fffu + ((x.u >> 16) & 1u);   // RNE
    return (unsigned short)(r >> 16);
}

__device__ __forceinline__ void gload16(const void* g, void* l) {
    __builtin_amdgcn_global_load_lds(
        (__attribute__((address_space(1))) void*)g,
        (__attribute__((address_space(3))) void*)l, 16, 0, 0);
}

// ---------------------------------------------------------------------------
// fp32 -> bf16 convert for x_in (16.7M), value_w (4.19M), output_w (4.19M)
// ---------------------------------------------------------------------------
__global__ __launch_bounds__(256) void convert_k(
    const float* __restrict__ x_in, const float* __restrict__ valw,
    const float* __restrict__ outw,
    ushort_t* __restrict__ xinB, ushort_t* __restrict__ valwB,
    ushort_t* __restrict__ outwB)
{
    size_t g = (size_t)blockIdx.x * 256 + threadIdx.x;
    const float* src; ushort_t* dst; size_t e;
    if (g < 4194304)      { src = x_in; dst = xinB;  e = g; }
    else if (g < 5242880) { src = valw; dst = valwB; e = g - 4194304; }
    else                  { src = outw; dst = outwB; e = g - 5242880; }
    const float4 v = ((const float4*)src)[e];
    us4 o; o.x = f2b(v.x); o.y = f2b(v.y); o.z = f2b(v.z); o.w = f2b(v.w);
    ((us4*)dst)[e] = o;
}

// ---------------------------------------------------------------------------
// BT GEMM: acc[m,n] = sum_k A[m,k]*B[n,k].  A,B bf16 row-major. K%32==0.
// MODE 1: outB = tanh(acc), guarded col<N
// MODE 2: outB = acc (bf16)
// MODE 3: w = cvec[col]+acc; outB = exp(w); inplace *= (1-exp(-exp(w)))
// MODE 4: token-shift mix: x=xB[idx], xp=shifted; out=(x+(xp-x)*(cvec+acc))[*cmul]
// MODE 5: outF = acc (fp32)  -- final output
// ---------------------------------------------------------------------------
template <int MODE>
__global__ __launch_bounds__(256) void gemm_bt_k(
    const ushort_t* __restrict__ A, int lda,
    const ushort_t* __restrict__ Bw, int ldb,
    int N, int K,
    ushort_t* __restrict__ outB, int ldc,
    const float* __restrict__ cvec,
    const float* __restrict__ cmul,
    const ushort_t* __restrict__ xBp,
    const float* __restrict__ shiftS,
    ushort_t* __restrict__ inplace,
    float* __restrict__ outF)
{
    __shared__ __align__(16) ushort_t At[128 * 32];
    __shared__ __align__(16) ushort_t Bt[128 * 32];

    const int tid  = threadIdx.x;
    const int wave = tid >> 6, lane = tid & 63;
    const int wm = wave >> 1, wn = wave & 1;
    const int fr = lane & 15, quad = lane >> 4;
    const int cr = lane >> 2;          // staging row within 16-row chunk
    const int cc = (lane & 3) * 8;     // staging col (elements)

    f32x4 acc[4][4];
#pragma unroll
    for (int i = 0; i < 4; ++i)
#pragma unroll
        for (int j = 0; j < 4; ++j)
#pragma unroll
            for (int r = 0; r < 4; ++r) acc[i][j][r] = 0.f;

    const int mbase = blockIdx.x * 128;
    const int nbase = blockIdx.y * 128;

    for (int k0 = 0; k0 < K; k0 += 32) {
        __syncthreads();
#pragma unroll
        for (int c2 = 0; c2 < 2; ++c2) {
            const int q  = wave * 2 + c2;
            const int ar = mbase + q * 16 + cr;
            gload16(A + (size_t)ar * lda + k0 + cc, &At[q * 512]);
            int br = nbase + q * 16 + cr;
            br = br < N ? br : N - 1;   // clamp for skinny-N
            gload16(Bw + (size_t)br * ldb + k0 + cc, &Bt[q * 512]);
        }
        __syncthreads();

        short8 af[4], bfr[4];
#pragma unroll
        for (int mi = 0; mi < 4; ++mi)
            af[mi] = *(const short8*)&At[(wm * 64 + mi * 16 + fr) * 32 + quad * 8];
#pragma unroll
        for (int ni = 0; ni < 4; ++ni)
            bfr[ni] = *(const short8*)&Bt[(wn * 64 + ni * 16 + fr) * 32 + quad * 8];
#pragma unroll
        for (int mi = 0; mi < 4; ++mi)
#pragma unroll
            for (int ni = 0; ni < 4; ++ni)
                acc[mi][ni] = __builtin_amdgcn_mfma_f32_16x16x32_bf16(
                    af[mi], bfr[ni], acc[mi][ni], 0, 0, 0);
    }

    // epilogue — C/D layout: col = lane&15, row = (lane>>4)*4 + reg  [m89]
    const int row0 = mbase + wm * 64 + quad * 4;
    const int col0 = nbase + wn * 64 + fr;
#pragma unroll
    for (int mi = 0; mi < 4; ++mi) {
#pragma unroll
        for (int ni = 0; ni < 4; ++ni) {
            const int col = col0 + ni * 16;
#pragma unroll
            for (int r = 0; r < 4; ++r) {
                const int row = row0 + mi * 16 + r;
                const float v = acc[mi][ni][r];
                const size_t idx = (size_t)row * ldc + col;
                if constexpr (MODE == 1) {
                    if (col < N) outB[idx] = f2b(tanhf(v));
                } else if constexpr (MODE == 2) {
                    outB[idx] = f2b(v);
                } else if constexpr (MODE == 3) {
                    const float w  = cvec[col] + v;
                    const float ew = __expf(w);
                    outB[idx] = f2b(ew);
                    inplace[idx] = f2b(b2f(inplace[idx]) * (1.f - __expf(-ew)));
                } else if constexpr (MODE == 4) {  // token-shift mix
                    const int t = row & (Tdim - 1);
                    const int b = row >> 11;
                    const float x  = b2f(xBp[idx]);
                    const float xp = (t > 0) ? b2f(xBp[idx - Cdim])
                                             : shiftS[(size_t)b * Cdim + col];
                    float val = x + (xp - x) * (cvec[col] + v);
                    if (cmul) val *= cmul[col];
                    outB[idx] = f2b(val);
                } else {  // MODE 5 — fp32 store (final output)
                    outF[idx] = v;
                }
            }
        }
    }
}

// ---------------------------------------------------------------------------
// All weight transposes (fp32 in -> bf16 transposed out), one launch.
// ---------------------------------------------------------------------------
__global__ __launch_bounds__(256) void transpose_all_k(
    const float* __restrict__ w1,  const float* __restrict__ ww1,
    const float* __restrict__ dw1, const float* __restrict__ dw2,
    const float* __restrict__ ww2, const float* __restrict__ w2,
    ushort_t* __restrict__ w1T,  ushort_t* __restrict__ ww1T,
    ushort_t* __restrict__ dw1T, ushort_t* __restrict__ dw2T,
    ushort_t* __restrict__ ww2T, ushort_t* __restrict__ w2T)
{
    int idx = blockIdx.x * 256 + threadIdx.x;
    if (idx < 262144) { int r = idx >> 7, c = idx & 127; w1T[c * 2048 + r] = f2b(w1[idx]); return; }
    idx -= 262144;
    if (idx < 65536)  { int r = idx >> 5, c = idx & 31;  ww1T[c * 2048 + r] = f2b(ww1[idx]); return; }
    idx -= 65536;
    if (idx < 262144) { int r = idx >> 7, c = idx & 127; dw1T[c * 2048 + r] = f2b(dw1[idx]); return; }
    idx -= 262144;
    if (idx < 262144) { int r = idx >> 11, c = idx & 2047; dw2T[c * 128 + r] = f2b(dw2[idx]); return; }
    idx -= 262144;
    if (idx < 65536)  { int r = idx >> 11, c = idx & 2047; ww2T[c * 32 + r] = f2b(ww2[idx]); return; }
    idx -= 65536;
    { int f = idx >> 16, rem = idx & 65535; int r = rem >> 11, c = rem & 2047;
      w2T[f * 65536 + c * 32 + r] = f2b(w2[idx]); }
}

// ---------------------------------------------------------------------------
// Sequential wkv6 (u=0): y_t[j] = sum_i r[i] S[i][j]; S = exp(-ew[i]) S + k[i] v[j]
// grid (128,4): blockIdx.x = h*4+jq, blockIdx.y = b. 64 threads, lane=jl*4+ip,
// lane owns S[i=ip*16+u][j=jq*16+jl]. y (bf16) aliases v (slice-local, one
// step ahead -> no hazard).
// ---------------------------------------------------------------------------
__global__ __launch_bounds__(64) void wkv_seq_k(
    const ushort_t* __restrict__ rB, const ushort_t* __restrict__ kB,
    const ushort_t* __restrict__ vB, const ushort_t* __restrict__ ewB,
    const float* __restrict__ s0, ushort_t* __restrict__ yB)
{
    const int hq = blockIdx.x;
    const int h = hq >> 2, jq = hq & 3;
    const int b = blockIdx.y;
    const int lane = threadIdx.x;
    const int jl = lane >> 2, ip = lane & 3;
    const int j = jq * 16 + jl;

    float S[16];
    const float* s0p = s0 + (((size_t)b * 32 + h) << 12);
#pragma unroll
    for (int u = 0; u < 16; ++u) S[u] = s0p[(ip * 16 + u) * 64 + j];

    __shared__ __align__(16) float rs[64];
    __shared__ __align__(16) float ks[64];
    __shared__ __align__(16) float dsh[64];
    __shared__ __align__(16) float vsh[16];

    const size_t base = ((size_t)b * Tdim) * Cdim + h * 64;
    const ushort_t* rg = rB + base;
    const ushort_t* kg = kB + base;
    const ushort_t* eg = ewB + base;
    const ushort_t* vg = vB + base + jq * 16;
    ushort_t* yg = yB + base + jq * 16;

    float pr = b2f(rg[lane]);
    float pk = b2f(kg[lane]);
    float pe = b2f(eg[lane]);
    float pv = (lane < 16) ? b2f(vg[lane]) : 0.f;

    size_t off = Cdim;
    for (int t = 0; t < Tdim; ++t) {
        rs[lane] = pr; ks[lane] = pk; dsh[lane] = __expf(-pe);
        if (lane < 16) vsh[lane] = pv;
        __syncthreads();
        if (t + 1 < Tdim) {
            pr = b2f(rg[off + lane]);
            pk = b2f(kg[off + lane]);
            pe = b2f(eg[off + lane]);
            if (lane < 16) pv = b2f(vg[off + lane]);
        }
        const float vj = vsh[jl];
        float y = 0.f;
#pragma unroll
        for (int a = 0; a < 4; ++a) {
            const float4 rr = *(const float4*)&rs[ip * 16 + a * 4];
            const float4 kk = *(const float4*)&ks[ip * 16 + a * 4];
            const float4 dd = *(const float4*)&dsh[ip * 16 + a * 4];
            y += rr.x * S[a * 4 + 0]; S[a * 4 + 0] = dd.x * S[a * 4 + 0] + kk.x * vj;
            y += rr.y * S[a * 4 + 1]; S[a * 4 + 1] = dd.y * S[a * 4 + 1] + kk.y * vj;
            y += rr.z * S[a * 4 + 2]; S[a * 4 + 2] = dd.z * S[a * 4 + 2] + kk.z * vj;
            y += rr.w * S[a * 4 + 3]; S[a * 4 + 3] = dd.w * S[a * 4 + 3] + kk.w * vj;
        }
        y += __shfl_xor(y, 1);
        y += __shfl_xor(y, 2);
        if (ip == 0) yg[(size_t)t * Cdim + jl] = f2b(y);
        off += Cdim;
        __syncthreads();
    }
}

// ---------------------------------------------------------------------------
// LayerNorm over C of (y + v2) -> bf16
// ---------------------------------------------------------------------------
__global__ __launch_bounds__(256) void ln_k(
    const ushort_t* __restrict__ yB, const ushort_t* __restrict__ v2,
    const float* __restrict__ gamma, const float* __restrict__ beta,
    ushort_t* __restrict__ out)
{
    const size_t base = (size_t)blockIdx.x * Cdim;
    const int tid = threadIdx.x;
    const int wave = tid >> 6, lane = tid & 63;

    float sum = 0.f, sq = 0.f;
    for (int c = tid; c < Cdim; c += 256) {
        const float s = b2f(yB[base + c]) + b2f(v2[base + c]);
        sum += s; sq += s * s;
    }
#pragma unroll
    for (int o = 1; o < 64; o <<= 1) {
        sum += __shfl_xor(sum, o);
        sq  += __shfl_xor(sq, o);
    }
    __shared__ float red[8];
    if (lane == 0) { red[wave] = sum; red[4 + wave] = sq; }
    __syncthreads();
    sum = red[0] + red[1] + red[2] + red[3];
    sq  = red[4] + red[5] + red[6] + red[7];
    const float mu  = sum * (1.f / Cdim);
    const float var = sq * (1.f / Cdim) - mu * mu;
    const float rsd = rsqrtf(var + 1e-5f);
    for (int c = tid; c < Cdim; c += 256) {
        const float s = b2f(yB[base + c]) + b2f(v2[base + c]);
        out[base + c] = f2b((s - mu) * rsd * gamma[c] + beta[c]);
    }
}

// ---------------------------------------------------------------------------
extern "C" void kernel_launch(void* const* d_in, const int* in_sizes, int n_in,
                              void* d_out, int out_size, void* d_ws, size_t ws_size,
                              hipStream_t stream)
{
    (void)in_sizes; (void)n_in; (void)out_size; (void)ws_size;
    const float* x_in   = (const float*)d_in[0];
    const float* shiftS = (const float*)d_in[1];
    const float* wkvS   = (const float*)d_in[2];
    const float* maa_r  = (const float*)d_in[3];
    const float* maa_k  = (const float*)d_in[4];
    const float* maa_v  = (const float*)d_in[5];
    const float* maa_v2 = (const float*)d_in[6];
    const float* maa_w1 = (const float*)d_in[7];
    const float* maa_w2 = (const float*)d_in[8];
    const float* maa_w  = (const float*)d_in[9];
    const float* ww1    = (const float*)d_in[10];
    const float* ww2    = (const float*)d_in[11];
    const float* tdecay = (const float*)d_in[12];
    const float* dw1    = (const float*)d_in[13];
    const float* dw2    = (const float*)d_in[14];
    const float* recep  = (const float*)d_in[16];
    const float* tkey   = (const float*)d_in[17];
    const float* valw   = (const float*)d_in[18];
    const float* outw   = (const float*)d_in[19];
    const float* gamma  = (const float*)d_in[20];
    const float* beta   = (const float*)d_in[21];

    // ---- workspace layout (~183 MB) ----
    char* ws = (char*)d_ws;
    const size_t MB = 1ull << 20;
    ushort_t* xB    = (ushort_t*)(ws + 0 * MB);     // 32 MB  x (bf16)
    ushort_t* mR    = (ushort_t*)(ws + 32 * MB);    // 32 MB  r -> y_ln
    ushort_t* mK    = (ushort_t*)(ws + 64 * MB);    // 32 MB  k
    ushort_t* mV2   = (ushort_t*)(ws + 96 * MB);    // 32 MB  v2
    ushort_t* xinB  = (ushort_t*)(ws + 128 * MB);   // 32 MB  x_in bf16; later mV/y
    ushort_t* mV    = xinB;                         //        (alias: xinB dead by then)
    ushort_t* valwB = (ushort_t*)(ws + 160 * MB);   // 8 MB
    ushort_t* outwB = (ushort_t*)(ws + 168 * MB);   // 8 MB
    char* sm = ws + 176 * MB;                       // small region (~7 MB)
    ushort_t* xxx   = (ushort_t*)(sm + 0);          // 8192x128 (2 MB)
    ushort_t* mwpre = (ushort_t*)(sm + 2097152);    // 8192x32  (512 KB)
    ushort_t* gbuf  = (ushort_t*)(sm + 2621440);    // 8192x128 (2 MB)
    ushort_t* w1T   = (ushort_t*)(sm + 4718592);    // 128x2048
    ushort_t* ww1T  = (ushort_t*)(sm + 5242880);    // 32x2048
    ushort_t* dw1T  = (ushort_t*)(sm + 5373952);    // 128x2048
    ushort_t* dw2T  = (ushort_t*)(sm + 5898240);    // 2048x128
    ushort_t* ww2T  = (ushort_t*)(sm + 6422528);    // 2048x32
    ushort_t* w2T   = (ushort_t*)(sm + 6553600);    // 4x 2048x32
    // xw -> ew bf16 scratch in d_out (33.5MB used of 67MB; dead before final
    // fp32 GEMM overwrites all of d_out)
    ushort_t* xwB = (ushort_t*)d_out;

    const dim3 blk(256);
    const float* NF = nullptr;
    const ushort_t* NUS = nullptr;
    ushort_t* NUM = nullptr;
    float* NFM = nullptr;

    // 0a) fp32 -> bf16 conversions
    convert_k<<<dim3(24576), blk, 0, stream>>>(x_in, valw, outw, xinB, valwB, outwB);
    // 0b) all weight transposes (fp32 -> bf16)
    transpose_all_k<<<dim3(4608), blk, 0, stream>>>(maa_w1, ww1, dw1, dw2, ww2, maa_w2,
                                                    w1T, ww1T, dw1T, dw2T, ww2T, w2T);
    // 1) x = x_in @ value_w^T (bf16)
    gemm_bt_k<2><<<dim3(64, 16), blk, 0, stream>>>(xinB, 2048, valwB, 2048, 2048, 2048,
                                                   xB, 2048, NF, NF, NUS, NF, NUM, NFM);
    // 2) xxx = tanh(x_in @ maa_w1)
    gemm_bt_k<1><<<dim3(64, 1), blk, 0, stream>>>(xinB, 2048, w1T, 2048, 128, 2048,
                                                  xxx, 128, NF, NF, NUS, NF, NUM, NFM);
    // 3) mwpre = tanh(x @ maa_w_w1)
    gemm_bt_k<1><<<dim3(64, 1), blk, 0, stream>>>(xB, 2048, ww1T, 2048, 32, 2048,
                                                  mwpre, 32, NF, NF, NUS, NF, NUM, NFM);
    // 4) mix GEMMs (K=32) with fused token-shift epilogue
    gemm_bt_k<4><<<dim3(64, 16), blk, 0, stream>>>(xxx + 0,  128, w2T + 0,      32, 2048, 32,
                                                   mR, 2048, maa_r, recep, xB, shiftS, NUM, NFM);
    gemm_bt_k<4><<<dim3(64, 16), blk, 0, stream>>>(xxx + 32, 128, w2T + 65536,  32, 2048, 32,
                                                   mK, 2048, maa_k, tkey, xB, shiftS, NUM, NFM);
    gemm_bt_k<4><<<dim3(64, 16), blk, 0, stream>>>(xxx + 64, 128, w2T + 131072, 32, 2048, 32,
                                                   mV, 2048, maa_v, NF, xB, shiftS, NUM, NFM);
    gemm_bt_k<4><<<dim3(64, 16), blk, 0, stream>>>(xxx + 96, 128, w2T + 196608, 32, 2048, 32,
                                                   mV2, 2048, maa_v2, NF, xB, shiftS, NUM, NFM);
    gemm_bt_k<4><<<dim3(64, 16), blk, 0, stream>>>(mwpre, 32, ww2T, 32, 2048, 32,
                                                   xwB, 2048, maa_w, NF, xB, shiftS, NUM, NFM);
    // 5) g = tanh(xw @ decay_w1)
    gemm_bt_k<1><<<dim3(64, 1), blk, 0, stream>>>(xwB, 2048, dw1T, 2048, 128, 2048,
                                                  gbuf, 128, NF, NF, NUS, NF, NUM, NFM);
    // 6) ew = exp(time_decay + g @ decay_w2) -> d_out;  k *= (1 - exp(-ew))
    gemm_bt_k<3><<<dim3(64, 16), blk, 0, stream>>>(gbuf, 128, dw2T, 128, 2048, 128,
                                                   xwB, 2048, tdecay, NF, NUS, NF, mK, NFM);
    // 7) wkv scan -> y (bf16, aliases v)
    wkv_seq_k<<<dim3(128, 4), dim3(64), 0, stream>>>(mR, mK, mV, xwB, wkvS, mV);
    // 8) LayerNorm(y + v2) -> y_ln (reuses mR)
    ln_k<<<dim3(8192), blk, 0, stream>>>(mV, mV2, gamma, beta, mR);
    // 9) out = y_ln @ output_w^T -> d_out as FP32
    gemm_bt_k<5><<<dim3(64, 16), blk, 0, stream>>>(mR, 2048, outwB, 2048, 2048, 2048,
                                                   NUM, 2048, NF, NF, NUS, NF, NUM,
                                                   (float*)d_out);
}